// Round 5
// baseline (266.460 us; speedup 1.0000x reference)
//
#include <hip/hip_runtime.h>
#include <cfloat>
#include <cmath>

// Problem: VectorQuantizer. inputs [16,8,512,64] fp32 (N=65536 rows, D=64),
// weight [512,64] fp32 (K=512). Outputs concat fp32:
//   [0] loss | [1..4194304] quantized_st | [4194305] perplexity | [4194306..] encodings (N*K)

#define OFF_LOSS  0
#define OFF_QUANT 1
#define OFF_PERP  4194305
#define OFF_ENC   4194306
#define VQ_EPS  1.1920929e-7f

// ws layout (u32): [0] sse(float) | [16..527] counts | [544..1055] wn (float)
#define WS_CNT 16
#define WS_WN  544

// init + precompute ||w_k||^2 (sequential-d fma order == previous per-lane
// order -> bit-identical distances downstream)
__global__ void vq_init(const float* __restrict__ w, unsigned* __restrict__ ws) {
    int t = threadIdx.x;  // 1024
    if (t < 544) ws[t] = 0u;
    if (t < 512) {
        const float4* wr = (const float4*)(w + (t << 6));
        float n = 0.f;
#pragma unroll
        for (int c = 0; c < 16; ++c) {
            float4 v = wr[c];
            n = fmaf(v.x, v.x, n);
            n = fmaf(v.y, v.y, n);
            n = fmaf(v.z, v.z, n);
            n = fmaf(v.w, v.w, n);
        }
        ((float*)ws)[WS_WN + t] = n;
    }
}

__global__ void __launch_bounds__(1024, 4)
vq_main(const float* __restrict__ x, const float* __restrict__ w,
        float* __restrict__ out, float* __restrict__ ws)
{
    extern __shared__ float smem[];
    float* wt   = smem;            // chunk-major W: float4 view [16 chunks][512 codes], 128 KB
    float* xlds = smem + 64 * 512; // [16 waves][8 rows][64], 32 KB

    const int t    = threadIdx.x;
    const int lane = t & 63;
    const int wid  = t >> 6;
    const float* wsf = (const float*)ws;

    // ---- stage W chunk-major (coalesced float4 global reads, b128 LDS writes)
    float4* wf4w = (float4*)wt;
#pragma unroll
    for (int i = 0; i < 8; ++i) {
        int e  = (t << 2) + (i << 12);       // element in w [512][64]
        float4 v = *(const float4*)(w + e);
        int k = e >> 6;
        int c = (e & 63) >> 2;
        wf4w[(c << 9) + k] = v;
    }

    // ---- per-lane ||w_k||^2 for codes k=j*64+lane (precomputed by vq_init)
    float wn[8];
#pragma unroll
    for (int j = 0; j < 8; ++j) wn[j] = wsf[WS_WN + (j << 6) + lane];

    __syncthreads();

    float sse = 0.f;
    const int waveRow0 = (blockIdx.x << 8) + (wid << 4);  // 256 rows/block, 16/wave
    float* myx = xlds + (wid << 9);                       // [8][64]
    const float4* wf4 = (const float4*)wt;
    const float4* xf4 = (const float4*)myx;

    for (int iter = 0; iter < 2; ++iter) {
        const int row0 = waveRow0 + (iter << 3);

        // ---- stage 8 rows of x (wave-private; DS ops in-order within wave)
        float xn_bc;
        {
            const float* src = x + ((size_t)row0 << 6) + (lane << 3);
            float4 a = *(const float4*)src;
            float4 b = *(const float4*)(src + 4);
            int r  = lane >> 3;
            int d0 = (lane & 7) << 3;
            *(float4*)(myx + (r << 6) + d0)     = a;
            *(float4*)(myx + (r << 6) + d0 + 4) = b;
            float pn = a.x*a.x + a.y*a.y + a.z*a.z + a.w*a.w
                     + b.x*b.x + b.y*b.y + b.z*b.z + b.w*b.w;
            pn += __shfl_xor(pn, 1);
            pn += __shfl_xor(pn, 2);
            pn += __shfl_xor(pn, 4);
            xn_bc = pn;  // lanes r*8..r*8+7 hold ||x_row(r)||^2
        }

        // ---- s[r][j] = x_row(row0+r) . w_code(j*64+lane), all-b128 LDS
        float s[8][8];
#pragma unroll
        for (int r = 0; r < 8; ++r)
#pragma unroll
            for (int j = 0; j < 8; ++j) s[r][j] = 0.f;

#pragma unroll 1
        for (int c = 0; c < 16; ++c) {
            float4 xq[8];
#pragma unroll
            for (int r = 0; r < 8; ++r) xq[r] = xf4[(r << 4) + c];  // broadcast
#pragma unroll
            for (int j = 0; j < 8; ++j) {
                float4 wq = wf4[(c << 9) + (j << 6) + lane];
#pragma unroll
                for (int r = 0; r < 8; ++r) {
                    // strict d-ascending accumulation (bit-exact vs reference path)
                    s[r][j] = fmaf(xq[r].x, wq.x, s[r][j]);
                    s[r][j] = fmaf(xq[r].y, wq.y, s[r][j]);
                    s[r][j] = fmaf(xq[r].z, wq.z, s[r][j]);
                    s[r][j] = fmaf(xq[r].w, wq.w, s[r][j]);
                }
            }
        }

        // ---- argmin per row (identical formula + tie-break)
        int bk_arr[8];
#pragma unroll
        for (int r = 0; r < 8; ++r) {
            float xn = __shfl(xn_bc, r << 3);
            float bv = FLT_MAX;
            int   bk = 0;
#pragma unroll
            for (int j = 0; j < 8; ++j) {
                float dv = (xn + wn[j]) - 2.0f * s[r][j];
                if (dv < bv) { bv = dv; bk = (j << 6) + lane; }
            }
#pragma unroll
            for (int off = 1; off < 64; off <<= 1) {
                float ov = __shfl_xor(bv, off);
                int   ok = __shfl_xor(bk, off);
                if (ov < bv || (ov == bv && ok < bk)) { bv = ov; bk = ok; }
            }
            bk_arr[r] = bk;
        }

        // ---- gather codebook rows (L2-resident)
        float wq[8];
#pragma unroll
        for (int r = 0; r < 8; ++r) wq[r] = w[((size_t)bk_arr[r] << 6) + lane];

        // ---- outputs: quantized_st, sse, one-hot (2x float4), histogram
#pragma unroll
        for (int r = 0; r < 8; ++r) {
            const int row = row0 + r;
            float xval = myx[(r << 6) + lane];
            float q    = wq[r];
            out[OFF_QUANT + ((size_t)row << 6) + lane] = xval + (q - xval);
            float df = q - xval;
            sse = fmaf(df, df, sse);

            int kk = bk_arr[r];
            int b  = lane << 3;
            float4 z0, z1;
            z0.x = (kk == b + 0) ? 1.f : 0.f;
            z0.y = (kk == b + 1) ? 1.f : 0.f;
            z0.z = (kk == b + 2) ? 1.f : 0.f;
            z0.w = (kk == b + 3) ? 1.f : 0.f;
            z1.x = (kk == b + 4) ? 1.f : 0.f;
            z1.y = (kk == b + 5) ? 1.f : 0.f;
            z1.z = (kk == b + 6) ? 1.f : 0.f;
            z1.w = (kk == b + 7) ? 1.f : 0.f;
            float4* ebase = (float4*)(out + OFF_ENC + ((size_t)row << 9) + (lane << 3));
            ebase[0] = z0;
            ebase[1] = z1;
            if (lane == r) atomicAdd(((unsigned*)ws) + WS_CNT + kk, 1u);
        }
    }

    // ---- loss partial
#pragma unroll
    for (int off = 1; off < 64; off <<= 1) sse += __shfl_xor(sse, off);
    if (lane == 0) atomicAdd((float*)ws, sse);
}

__global__ void vq_fin(const unsigned* __restrict__ ws, float* __restrict__ out)
{
    __shared__ float red[8];
    int t = threadIdx.x;   // 512 threads
    unsigned c = ws[WS_CNT + t];
    float p = (float)c * (1.0f / 65536.0f);
    float v = p * logf(p + VQ_EPS);
#pragma unroll
    for (int off = 1; off < 64; off <<= 1) v += __shfl_xor(v, off);
    if ((t & 63) == 0) red[t >> 6] = v;
    __syncthreads();
    if (t == 0) {
        float s2 = 0.f;
#pragma unroll
        for (int i = 0; i < 8; ++i) s2 += red[i];
        out[OFF_PERP] = expf(-s2);
        float sse = ((const float*)ws)[0];
        float m = sse * (1.0f / 4194304.0f);
        out[OFF_LOSS] = m + 0.25f * m;
    }
}

extern "C" void kernel_launch(void* const* d_in, const int* in_sizes, int n_in,
                              void* d_out, int out_size, void* d_ws, size_t ws_size,
                              hipStream_t stream) {
    const float* x = (const float*)d_in[0];
    const float* w = (const float*)d_in[1];
    float* out = (float*)d_out;
    unsigned* ws = (unsigned*)d_ws;

    const size_t smem = (size_t)(64 * 512 + 16 * 8 * 64) * 4;  // 160 KiB exactly
    (void)hipFuncSetAttribute((const void*)vq_main,
                              hipFuncAttributeMaxDynamicSharedMemorySize, (int)smem);

    hipLaunchKernelGGL(vq_init, dim3(1), dim3(1024), 0, stream, w, ws);
    hipLaunchKernelGGL(vq_main, dim3(256), dim3(1024), smem, stream, x, w, out, (float*)ws);
    hipLaunchKernelGGL(vq_fin,  dim3(1), dim3(512), 0, stream, ws, out);
}

// Round 6
// 264.571 us; speedup vs baseline: 1.0071x; 1.0071x over previous
//
#include <hip/hip_runtime.h>
#include <cfloat>
#include <cmath>

// Problem: VectorQuantizer. inputs [16,8,512,64] fp32 (N=65536 rows, D=64),
// weight [512,64] fp32 (K=512). Outputs concat fp32:
//   [0] loss | [1..4194304] quantized_st | [4194305] perplexity | [4194306..] encodings (N*K)

#define OFF_LOSS  0
#define OFF_QUANT 1
#define OFF_PERP  4194305
#define OFF_ENC   4194306
#define VQ_EPS  1.1920929e-7f

// ws layout (u32): [0] sse(float) | [16..527] counts | [544..1055] wn (float)
#define WS_CNT 16
#define WS_WN  544

// init + precompute ||w_k||^2 (sequential-d fma order -> bit-identical
// distances downstream; validated absmax 0.0 in round 5)
__global__ void vq_init(const float* __restrict__ w, unsigned* __restrict__ ws) {
    int t = threadIdx.x;  // 1024
    if (t < 544) ws[t] = 0u;
    if (t < 512) {
        const float4* wr = (const float4*)(w + (t << 6));
        float n = 0.f;
#pragma unroll
        for (int c = 0; c < 16; ++c) {
            float4 v = wr[c];
            n = fmaf(v.x, v.x, n);
            n = fmaf(v.y, v.y, n);
            n = fmaf(v.z, v.z, n);
            n = fmaf(v.w, v.w, n);
        }
        ((float*)ws)[WS_WN + t] = n;
    }
}

__global__ void __launch_bounds__(1024, 4)
vq_main(const float* __restrict__ x, const float* __restrict__ w,
        float* __restrict__ out, float* __restrict__ ws)
{
    extern __shared__ float smem[];
    float* wt   = smem;            // chunk-major W, float4 view [16][512], code k at k^(c&7); 128 KB
    float* xlds = smem + 64 * 512; // [16 waves][8 rows][64], 32 KB

    const int t    = threadIdx.x;
    const int lane = t & 63;
    const int wid  = t >> 6;
    const float* wsf = (const float*)ws;

    // ---- stage W: coalesced global float4 reads; LDS write idx XOR-swizzled
    //      so the 16 lanes of a phase hit distinct bank quads (was 16-way).
    {
        float4* wf4w = (float4*)wt;
        const float4* w4 = (const float4*)w;
#pragma unroll
        for (int i = 0; i < 8; ++i) {
            int e = t + (i << 10);           // float4 index into w [512][16]
            int k = e >> 4;
            int c = e & 15;
            wf4w[(c << 9) + (k ^ (c & 7))] = w4[e];
        }
    }

    // ---- per-lane ||w_k||^2 for codes k=j*64+lane (precomputed by vq_init)
    float wn[8];
#pragma unroll
    for (int j = 0; j < 8; ++j) wn[j] = wsf[WS_WN + (j << 6) + lane];

    __syncthreads();

    float sse = 0.f;
    const int waveRow0 = (blockIdx.x << 8) + (wid << 4);  // 256 rows/block, 16/wave
    float* myx = xlds + (wid << 9);                       // [8][64]
    const float4* wf4 = (const float4*)wt;
    const float4* xf4 = (const float4*)myx;

    for (int iter = 0; iter < 2; ++iter) {
        const int row0 = waveRow0 + (iter << 3);

        // ---- stage 8 rows of x (wave-private; DS ops in-order within wave)
        float xn_bc;
        {
            const float* src = x + ((size_t)row0 << 6) + (lane << 3);
            float4 a = *(const float4*)src;
            float4 b = *(const float4*)(src + 4);
            int r  = lane >> 3;
            int d0 = (lane & 7) << 3;
            *(float4*)(myx + (r << 6) + d0)     = a;
            *(float4*)(myx + (r << 6) + d0 + 4) = b;
            float pn = a.x*a.x + a.y*a.y + a.z*a.z + a.w*a.w
                     + b.x*b.x + b.y*b.y + b.z*b.z + b.w*b.w;
            pn += __shfl_xor(pn, 1);
            pn += __shfl_xor(pn, 2);
            pn += __shfl_xor(pn, 4);
            xn_bc = pn;  // lanes r*8..r*8+7 hold ||x_row(r)||^2
        }

        // ---- distances, j-blocked (4 codes/lane at a time -> regs fit):
        //      running per-row argmin folded between halves; scan order is
        //      j ascending == k ascending per lane (tie-break preserved).
        float bv[8]; int bk[8];
#pragma unroll
        for (int r = 0; r < 8; ++r) { bv[r] = FLT_MAX; bk[r] = 0; }

#pragma unroll
        for (int jh = 0; jh < 2; ++jh) {
            float s[8][4];
#pragma unroll
            for (int r = 0; r < 8; ++r)
#pragma unroll
                for (int jj = 0; jj < 4; ++jj) s[r][jj] = 0.f;

#pragma unroll 2
            for (int c = 0; c < 16; ++c) {
                const int lofs = (c << 9) + (jh << 8) + (lane ^ (c & 7));
                float4 wq4[4];
#pragma unroll
                for (int jj = 0; jj < 4; ++jj) wq4[jj] = wf4[lofs + (jj << 6)];
#pragma unroll
                for (int r = 0; r < 8; ++r) {
                    float4 xq = xf4[(r << 4) + c];   // broadcast read
#pragma unroll
                    for (int jj = 0; jj < 4; ++jj) {
                        // strict d-ascending accumulation (bit-exact)
                        s[r][jj] = fmaf(xq.x, wq4[jj].x, s[r][jj]);
                        s[r][jj] = fmaf(xq.y, wq4[jj].y, s[r][jj]);
                        s[r][jj] = fmaf(xq.z, wq4[jj].z, s[r][jj]);
                        s[r][jj] = fmaf(xq.w, wq4[jj].w, s[r][jj]);
                    }
                }
            }

#pragma unroll
            for (int r = 0; r < 8; ++r) {
                float xn = __shfl(xn_bc, r << 3);
#pragma unroll
                for (int jj = 0; jj < 4; ++jj) {
                    const int j = (jh << 2) + jj;
                    float dv = (xn + wn[j]) - 2.0f * s[r][jj];
                    if (dv < bv[r]) { bv[r] = dv; bk[r] = (j << 6) + lane; }
                }
            }
        }

        // ---- cross-lane argmin butterfly (identical tie-break)
        int bk_arr[8];
#pragma unroll
        for (int r = 0; r < 8; ++r) {
            float v = bv[r]; int k = bk[r];
#pragma unroll
            for (int off = 1; off < 64; off <<= 1) {
                float ov = __shfl_xor(v, off);
                int   ok = __shfl_xor(k, off);
                if (ov < v || (ov == v && ok < k)) { v = ov; k = ok; }
            }
            bk_arr[r] = k;
        }

        // ---- gather codebook rows (L2-resident)
        float wq[8];
#pragma unroll
        for (int r = 0; r < 8; ++r) wq[r] = w[((size_t)bk_arr[r] << 6) + lane];

        // ---- outputs: quantized_st, sse, one-hot (2x float4), histogram
#pragma unroll
        for (int r = 0; r < 8; ++r) {
            const int row = row0 + r;
            float xval = myx[(r << 6) + lane];
            float q    = wq[r];
            out[OFF_QUANT + ((size_t)row << 6) + lane] = xval + (q - xval);
            float df = q - xval;
            sse = fmaf(df, df, sse);

            int kk = bk_arr[r];
            int b  = lane << 3;
            float4 z0, z1;
            z0.x = (kk == b + 0) ? 1.f : 0.f;
            z0.y = (kk == b + 1) ? 1.f : 0.f;
            z0.z = (kk == b + 2) ? 1.f : 0.f;
            z0.w = (kk == b + 3) ? 1.f : 0.f;
            z1.x = (kk == b + 4) ? 1.f : 0.f;
            z1.y = (kk == b + 5) ? 1.f : 0.f;
            z1.z = (kk == b + 6) ? 1.f : 0.f;
            z1.w = (kk == b + 7) ? 1.f : 0.f;
            float4* ebase = (float4*)(out + OFF_ENC + ((size_t)row << 9) + (lane << 3));
            ebase[0] = z0;
            ebase[1] = z1;
            if (lane == r) atomicAdd(((unsigned*)ws) + WS_CNT + kk, 1u);
        }
    }

    // ---- loss partial
#pragma unroll
    for (int off = 1; off < 64; off <<= 1) sse += __shfl_xor(sse, off);
    if (lane == 0) atomicAdd((float*)ws, sse);
}

__global__ void vq_fin(const unsigned* __restrict__ ws, float* __restrict__ out)
{
    __shared__ float red[8];
    int t = threadIdx.x;   // 512 threads
    unsigned c = ws[WS_CNT + t];
    float p = (float)c * (1.0f / 65536.0f);
    float v = p * logf(p + VQ_EPS);
#pragma unroll
    for (int off = 1; off < 64; off <<= 1) v += __shfl_xor(v, off);
    if ((t & 63) == 0) red[t >> 6] = v;
    __syncthreads();
    if (t == 0) {
        float s2 = 0.f;
#pragma unroll
        for (int i = 0; i < 8; ++i) s2 += red[i];
        out[OFF_PERP] = expf(-s2);
        float sse = ((const float*)ws)[0];
        float m = sse * (1.0f / 4194304.0f);
        out[OFF_LOSS] = m + 0.25f * m;
    }
}

extern "C" void kernel_launch(void* const* d_in, const int* in_sizes, int n_in,
                              void* d_out, int out_size, void* d_ws, size_t ws_size,
                              hipStream_t stream) {
    const float* x = (const float*)d_in[0];
    const float* w = (const float*)d_in[1];
    float* out = (float*)d_out;
    unsigned* ws = (unsigned*)d_ws;

    const size_t smem = (size_t)(64 * 512 + 16 * 8 * 64) * 4;  // 160 KiB exactly
    (void)hipFuncSetAttribute((const void*)vq_main,
                              hipFuncAttributeMaxDynamicSharedMemorySize, (int)smem);

    hipLaunchKernelGGL(vq_init, dim3(1), dim3(1024), 0, stream, w, ws);
    hipLaunchKernelGGL(vq_main, dim3(256), dim3(1024), smem, stream, x, w, out, (float*)ws);
    hipLaunchKernelGGL(vq_fin,  dim3(1), dim3(512), 0, stream, ws, out);
}